// Round 13
// baseline (853.926 us; speedup 1.0000x reference)
//
// R11: GEMM with convert∥MFMA overlap. LDS: sA 32K single + sBf 32K single
// + sB32 64K dbuf. Phase 1: ALL frags -> regs (sA,sBf consumed) -> bar ->
// issue ld16 A(kt+1)->sA, B32(kt+2)->sB32[flip]; convert B32(kt+1)->sBf
// OVERLAPPED with 96 reg-only MFMAs -> lgkm(0), vmcnt(0), bar.
// Convert math/layout bit-identical to R10 (absmax canary 0.03125).
// Everything outside gemm identical to R10 (passed, 566us).
#include <hip/hip_runtime.h>
#include <hip/hip_bf16.h>
#include <stdint.h>

#define NB    1024
#define NT    4
#define NDIN  768
#define NSAE  16384
#define NK    64
#define KDIM  3072
#define PFX0  8192
#define KT96  96          // K-steps of 32 real K
#define VKD   6144        // virtual K per row of A2 (2*KDIM)

typedef _Float16 f16x8 __attribute__((ext_vector_type(8)));
typedef _Float16 f16x4 __attribute__((ext_vector_type(4)));
typedef float    f32x4 __attribute__((ext_vector_type(4)));

__device__ __forceinline__ unsigned f2key(float f) {
    union { float f; unsigned u; } cv; cv.f = f;
    unsigned u = cv.u;
    return u ^ ((unsigned)((int)u >> 31) | 0x80000000u);  // monotonic float->uint
}

__device__ __forceinline__ void ld16(const void* g, void* l) {
    __builtin_amdgcn_global_load_lds(
        (const __attribute__((address_space(1))) void*)g,
        (__attribute__((address_space(3))) void*)l, 16, 0, 0);
}

// ---------------- A split conversion (interleaved layout) ----------------
__global__ __launch_bounds__(256) void conv_a_kernel(
    const float* __restrict__ A, _Float16* __restrict__ A2)
{
    const int gid = blockIdx.x * 256 + threadIdx.x;
    const int m = gid / (KDIM / 4);
    const int k = (gid % (KDIM / 4)) * 4;
    const float4 v = *(const float4*)(A + (size_t)m * KDIM + k);
    const float vv[4] = { v.x, v.y, v.z, v.w };
    f16x4 h, l;
#pragma unroll
    for (int j = 0; j < 4; ++j) {
        const float sv = vv[j] * 64.f;
        const _Float16 hh = (_Float16)sv;
        h[j] = hh;
        l[j] = (_Float16)(sv - (float)hh);      // unboosted
    }
    const size_t ob = (size_t)m * VKD + (k >> 5) * 64 + (k & 31);
    *(f16x4*)(A2 + ob)      = h;
    *(f16x4*)(A2 + ob + 32) = l;
}

// ---------------- MFMA GEMM: pre = (A @ B) + bias, emulated f32 ----------------
__global__ __launch_bounds__(512, 1) void gemm_f16split_kernel(
    const _Float16* __restrict__ A2, const float* __restrict__ Bsrc,
    const float* __restrict__ bias, float* __restrict__ pre)
{
    __shared__ _Float16 sA[256 * 64];        // 32KB single
    __shared__ _Float16 sBf[256 * 64];       // 32KB single
    __shared__ float    sB32[2 * 32 * 256];  // 64KB dbuf
    const int tid = threadIdx.x;
    const int lane = tid & 63;
    const int wid = tid >> 6;     // 0..7
    const int wm = wid >> 2;      // 0..1  (M half)
    const int wn = wid & 3;       // 0..3  (N quarter)

    // T1 chunked XCD swizzle: 256 blocks, bijective.
    const int bid = blockIdx.x;
    const int swz = (bid & 7) * 32 + (bid >> 3);
    const int m0 = (swz & 3) * 256;
    const int n0 = (swz >> 2) * 256;

    // staging pointers; LDS dest linear (ld16 HW constraint).
    const _Float16* pa[4]; const float* pb[4];
    _Float16* da[4]; float* db[4];
#pragma unroll
    for (int r = 0; r < 4; ++r) {
        const int d = tid + r * 512;
        const int rowA = d >> 3;
        const int lsA = (d & 7) ^ (rowA & 7);
        pa[r] = A2 + (size_t)(m0 + rowA) * VKD + lsA * 8;
        da[r] = sA + d * 8;
        const int kB = d >> 6;
        const int slotB = d & 63;
        pb[r] = Bsrc + (size_t)kB * NSAE + n0 + slotB * 4;
        db[r] = sB32 + d * 4;                 // buf0; buf1 = +8192 f32
    }

    // fragment read offsets (XOR-8 swizzled)
    const int rl = lane & 15;
    const int qw = lane >> 4;
    const int off0 = ((0 + qw) ^ (rl & 7)) * 8 + rl * 64;   // hi limb
    const int off1 = ((4 + qw) ^ (rl & 7)) * 8 + rl * 64;   // lo limb

    // convert-phase mapping (identical math to R10)
    const int cvn = tid & 255;
    const int cvkh = tid >> 8;
    const int cvsw = cvn & 7;
    _Float16* const cvout = sBf + cvn * 64;

#define CONVERT(half)                                                         \
    {                                                                         \
        const int cvb = (half) * 8192;                                        \
        float v[16];                                                          \
        _Pragma("unroll")                                                     \
        for (int j = 0; j < 16; ++j)                                          \
            v[j] = sB32[cvb + (cvkh * 16 + j) * 256 + cvn];                   \
        f16x8 h0{}, h1{}, l0{}, l1{};                                         \
        _Pragma("unroll")                                                     \
        for (int j = 0; j < 8; ++j) {                                         \
            const float sv = v[j] * 64.f;                                     \
            const _Float16 hh = (_Float16)sv;                                 \
            h0[j] = hh;                                                       \
            l0[j] = (_Float16)(sv - (float)hh);                               \
        }                                                                     \
        _Pragma("unroll")                                                     \
        for (int j = 0; j < 8; ++j) {                                         \
            const float sv = v[8 + j] * 64.f;                                 \
            const _Float16 hh = (_Float16)sv;                                 \
            h1[j] = hh;                                                       \
            l1[j] = (_Float16)(sv - (float)hh);                               \
        }                                                                     \
        *(f16x8*)(cvout + (((cvkh * 2 + 0) ^ cvsw) * 8)) = h0;                \
        *(f16x8*)(cvout + (((cvkh * 2 + 1) ^ cvsw) * 8)) = h1;                \
        *(f16x8*)(cvout + (((4 + cvkh * 2 + 0) ^ cvsw) * 8)) = l0;            \
        *(f16x8*)(cvout + (((4 + cvkh * 2 + 1) ^ cvsw) * 8)) = l1;            \
    }

    f32x4 acc[8][4];
#pragma unroll
    for (int mi = 0; mi < 8; ++mi)
#pragma unroll
        for (int ni = 0; ni < 4; ++ni)
            acc[mi][ni] = (f32x4){0.f, 0.f, 0.f, 0.f};

    const size_t KSTRB = (size_t)32 * NSAE;

    // prologue: A(0)->sA, B32(0)->buf0, B32(1)->buf1; convert Bf(0)
#pragma unroll
    for (int r = 0; r < 4; ++r) {
        ld16(pa[r], da[r]);
        ld16(pb[r], db[r]);
        ld16(pb[r] + KSTRB, db[r] + 8192);
    }
    asm volatile("s_waitcnt vmcnt(0)" ::: "memory");
    __builtin_amdgcn_sched_barrier(0);
    __builtin_amdgcn_s_barrier();
    __builtin_amdgcn_sched_barrier(0);
    CONVERT(0)
    asm volatile("s_waitcnt lgkmcnt(0)" ::: "memory");
    __builtin_amdgcn_sched_barrier(0);
    __builtin_amdgcn_s_barrier();
    __builtin_amdgcn_sched_barrier(0);

    for (int kt = 0; kt < KT96; ++kt) {
        // ===== phase 1: ALL fragments -> registers (consumes sA, sBf) =====
        f16x8 af[8][2], bf[4][2];
#pragma unroll
        for (int mi = 0; mi < 8; ++mi) {
            const int ra = (wm * 128 + mi * 16) * 64;
            af[mi][0] = *(const f16x8*)(sA + ra + off0);
            af[mi][1] = *(const f16x8*)(sA + ra + off1);
        }
#pragma unroll
        for (int ni = 0; ni < 4; ++ni) {
            const int rb = (wn * 64 + ni * 16) * 64;
            bf[ni][0] = *(const f16x8*)(sBf + rb + off0);
            bf[ni][1] = *(const f16x8*)(sBf + rb + off1);
        }
        asm volatile("s_waitcnt lgkmcnt(0)" ::: "memory");
        __builtin_amdgcn_sched_barrier(0);
        __builtin_amdgcn_s_barrier();            // sA & sBf consumed everywhere
        __builtin_amdgcn_sched_barrier(0);

        // ===== phase 2: issue next-tile loads (hidden under MFMA) =====
        if (kt + 1 < KT96) {
            const int koA = (kt + 1) * 64;
#pragma unroll
            for (int r = 0; r < 4; ++r) ld16(pa[r] + koA, da[r]);
        }
        if (kt + 2 < KT96) {
            const size_t koB = (size_t)(kt + 2) * KSTRB;
            const int bb = (kt & 1) * 8192;      // (kt+2)&1 == kt&1
#pragma unroll
            for (int r = 0; r < 4; ++r) ld16(pb[r] + koB, db[r] + bb);
        }

        // ===== phase 3: convert Bf(kt+1) OVERLAPPED with MFMAs =====
        if (kt + 1 < KT96) CONVERT((kt + 1) & 1)

        __builtin_amdgcn_s_setprio(1);
#pragma unroll
        for (int mi = 0; mi < 8; ++mi)
#pragma unroll
            for (int ni = 0; ni < 4; ++ni) {
                acc[mi][ni] = __builtin_amdgcn_mfma_f32_16x16x32_f16(af[mi][0], bf[ni][0], acc[mi][ni], 0, 0, 0);
                acc[mi][ni] = __builtin_amdgcn_mfma_f32_16x16x32_f16(af[mi][0], bf[ni][1], acc[mi][ni], 0, 0, 0);
                acc[mi][ni] = __builtin_amdgcn_mfma_f32_16x16x32_f16(af[mi][1], bf[ni][0], acc[mi][ni], 0, 0, 0);
            }
        __builtin_amdgcn_s_setprio(0);

        // ===== phase 4: drain & flip =====
        __builtin_amdgcn_sched_barrier(0);
        asm volatile("s_waitcnt lgkmcnt(0)" ::: "memory");   // convert writes done
        asm volatile("s_waitcnt vmcnt(0)" ::: "memory");     // next A + B32 landed
        __builtin_amdgcn_sched_barrier(0);
        __builtin_amdgcn_s_barrier();
        __builtin_amdgcn_sched_barrier(0);
    }
#undef CONVERT

    // epilogue: pre = acc*2^-12 + bias
    const float c12 = 1.0f / 4096.0f;
    float bv[4];
#pragma unroll
    for (int ni = 0; ni < 4; ++ni) bv[ni] = bias[n0 + wn * 64 + ni * 16 + rl];
#pragma unroll
    for (int mi = 0; mi < 8; ++mi)
#pragma unroll
        for (int ni = 0; ni < 4; ++ni)
#pragma unroll
            for (int r = 0; r < 4; ++r) {
                const int row = m0 + wm * 128 + mi * 16 + qw * 4 + r;
                const int col = n0 + wn * 64 + ni * 16 + rl;
                pre[(size_t)row * NSAE + col] = acc[mi][ni][r] * c12 + bv[ni];
            }
}

// ---------------- f32 fallback GEMM (R1, known-good) ----------------
__global__ __launch_bounds__(256) void gemm_pre_kernel(
    const float* __restrict__ A, const float* __restrict__ Bm,
    const float* __restrict__ bias, float* __restrict__ pre)
{
    __shared__ float As[16][128];
    __shared__ float Bs[16][128];
    const int bn = blockIdx.x * 128;
    const int bm = blockIdx.y * 128;
    const int tid = threadIdx.x;
    const int tx = tid & 15;
    const int ty = tid >> 4;

    float acc[8][8];
#pragma unroll
    for (int i = 0; i < 8; ++i)
#pragma unroll
        for (int j = 0; j < 8; ++j) acc[i][j] = 0.f;

    for (int k0 = 0; k0 < KDIM; k0 += 16) {
#pragma unroll
        for (int i = 0; i < 2; ++i) {
            const int idx = i * 256 + tid;
            const int r = idx >> 2;
            const int c = (idx & 3) << 2;
            const float4 v = *(const float4*)(A + (size_t)(bm + r) * KDIM + (k0 + c));
            As[c + 0][r] = v.x; As[c + 1][r] = v.y;
            As[c + 2][r] = v.z; As[c + 3][r] = v.w;
        }
#pragma unroll
        for (int i = 0; i < 2; ++i) {
            const int idx = i * 256 + tid;
            const int r = idx >> 5;
            const int c = (idx & 31) << 2;
            *(float4*)(&Bs[r][c]) = *(const float4*)(Bm + (size_t)(k0 + r) * NSAE + (bn + c));
        }
        __syncthreads();
#pragma unroll
        for (int kk = 0; kk < 16; ++kk) {
            const float4 a0 = *(const float4*)(&As[kk][ty * 8]);
            const float4 a1 = *(const float4*)(&As[kk][ty * 8 + 4]);
            const float4 b0 = *(const float4*)(&Bs[kk][tx * 8]);
            const float4 b1 = *(const float4*)(&Bs[kk][tx * 8 + 4]);
            const float av[8] = { a0.x, a0.y, a0.z, a0.w, a1.x, a1.y, a1.z, a1.w };
            const float bv[8] = { b0.x, b0.y, b0.z, b0.w, b1.x, b1.y, b1.z, b1.w };
#pragma unroll
            for (int i = 0; i < 8; ++i)
#pragma unroll
                for (int j = 0; j < 8; ++j)
                    acc[i][j] = fmaf(av[i], bv[j], acc[i][j]);
        }
        __syncthreads();
    }

    float bv8[8];
#pragma unroll
    for (int j = 0; j < 8; ++j) bv8[j] = bias[bn + tx * 8 + j];
#pragma unroll
    for (int i = 0; i < 8; ++i) {
        float4 o0, o1;
        o0.x = acc[i][0] + bv8[0]; o0.y = acc[i][1] + bv8[1];
        o0.z = acc[i][2] + bv8[2]; o0.w = acc[i][3] + bv8[3];
        o1.x = acc[i][4] + bv8[4]; o1.y = acc[i][5] + bv8[5];
        o1.z = acc[i][6] + bv8[6]; o1.w = acc[i][7] + bv8[7];
        const size_t off = (size_t)(bm + ty * 8 + i) * NSAE + bn + tx * 8;
        *(float4*)(pre + off) = o0;
        *(float4*)(pre + off + 4) = o1;
    }
}

// ---------------- per-row radix top-64, row held in registers ----------------
__global__ __launch_bounds__(256) void topk_kernel(
    const float* __restrict__ pre,
    int* __restrict__ tk_idx, float* __restrict__ tk_val,
    float* __restrict__ z)
{
    __shared__ unsigned hist[4][256];
    __shared__ int sel[NK];
    __shared__ float sval[NK];
    __shared__ int ties[256];
    __shared__ float tval[256];
    __shared__ unsigned sh_prefix, sh_want, sh_cnt, sh_tiecnt;

    const int b = blockIdx.x;
    const int tid = threadIdx.x;
    const int w = tid >> 6;
    const float* row = pre + (size_t)b * NSAE;
    float* zrow = z + (size_t)b * NSAE;

    if (tid == 0) { sh_prefix = 0u; sh_want = NK; sh_cnt = 0u; sh_tiecnt = 0u; }
    hist[0][tid] = 0u; hist[1][tid] = 0u; hist[2][tid] = 0u; hist[3][tid] = 0u;
    __syncthreads();

    float4 rv[16];
#pragma unroll
    for (int j = 0; j < 16; ++j) {
        const int i = tid * 4 + j * 1024;
        rv[j] = *(const float4*)(row + i);
        *(float4*)(zrow + i) = make_float4(0.f, 0.f, 0.f, 0.f);
        atomicAdd(&hist[w][f2key(rv[j].x) >> 24], 1u);
        atomicAdd(&hist[w][f2key(rv[j].y) >> 24], 1u);
        atomicAdd(&hist[w][f2key(rv[j].z) >> 24], 1u);
        atomicAdd(&hist[w][f2key(rv[j].w) >> 24], 1u);
    }
    __syncthreads();
    hist[0][tid] += hist[1][tid] + hist[2][tid] + hist[3][tid];
    __syncthreads();
    if (tid == 0) {
        unsigned cum = 0u; int bsel = 0;
        for (int bin = 255; bin >= 0; --bin) {
            const unsigned c = hist[0][bin];
            if (cum + c >= NK) { bsel = bin; break; }
            cum += c;
        }
        sh_prefix = ((unsigned)bsel << 24);
        sh_want = NK - cum;
    }
    __syncthreads();

    for (int pass = 1; pass < 4; ++pass) {
        hist[0][tid] = 0u; hist[1][tid] = 0u; hist[2][tid] = 0u; hist[3][tid] = 0u;
        __syncthreads();
        const int shift = 24 - pass * 8;
        const unsigned mask = 0xFFFFFFFFu << (shift + 8);
        const unsigned pfx = sh_prefix;
#pragma unroll
        for (int j = 0; j < 16; ++j) {
            const float fv[4] = { rv[j].x, rv[j].y, rv[j].z, rv[j].w };
#pragma unroll
            for (int q = 0; q < 4; ++q) {
                const unsigned k = f2key(fv[q]);
                if ((k & mask) == pfx) atomicAdd(&hist[w][(k >> shift) & 0xFFu], 1u);
            }
        }
        __syncthreads();
        hist[0][tid] += hist[1][tid] + hist[2][tid] + hist[3][tid];
        __syncthreads();
        if (tid == 0) {
            const unsigned want = sh_want;
            unsigned cum = 0u; int bsel = 0;
            for (int bin = 255; bin >= 0; --bin) {
                const unsigned c = hist[0][bin];
                if (cum + c >= want) { bsel = bin; break; }
                cum += c;
            }
            sh_prefix |= ((unsigned)bsel << shift);
            sh_want = want - cum;
        }
        __syncthreads();
    }

    const unsigned T = sh_prefix;
#pragma unroll
    for (int j = 0; j < 16; ++j) {
        const float fv[4] = { rv[j].x, rv[j].y, rv[j].z, rv[j].w };
#pragma unroll
        for (int q = 0; q < 4; ++q) {
            const unsigned k = f2key(fv[q]);
            if (k > T) {
                const unsigned s = atomicAdd(&sh_cnt, 1u);
                sel[s] = tid * 4 + j * 1024 + q;
                sval[s] = fv[q];
            } else if (k == T) {
                const unsigned s = atomicAdd(&sh_tiecnt, 1u);
                if (s < 256u) { ties[s] = tid * 4 + j * 1024 + q; tval[s] = fv[q]; }
            }
        }
    }
    __syncthreads();
    if (tid == 0) {
        const unsigned tc = sh_tiecnt;
        const int n = (int)(tc < 256u ? tc : 256u);
        for (int a = 1; a < n; ++a) {
            const int v = ties[a]; const float fv = tval[a]; int c = a;
            while (c > 0 && ties[c - 1] > v) {
                ties[c] = ties[c - 1]; tval[c] = tval[c - 1]; --c;
            }
            ties[c] = v; tval[c] = fv;
        }
        const int base = (int)sh_cnt;
        const int want = (int)sh_want;
        for (int j = 0; j < want && j < n; ++j) {
            sel[base + j] = ties[j]; sval[base + j] = tval[j];
        }
    }
    __syncthreads();
    if (tid < NK) {
        const int myi = sel[tid];
        int rank = 0;
#pragma unroll 1
        for (int j = 0; j < NK; ++j) rank += (sel[j] < myi) ? 1 : 0;
        const float v = fmaxf(sval[tid], 0.f);
        tk_idx[b * NK + rank] = myi;
        tk_val[b * NK + rank] = v;
        zrow[myi] = v;
    }
}

// ---------------- inverse permutation ----------------
__global__ __launch_bounds__(256) void invperm_kernel(
    const int* __restrict__ perm, int* __restrict__ ipos)
{
    const int i = blockIdx.x * 256 + threadIdx.x;
    if (i < NT * NSAE) {
        const int t = i >> 14;
        ipos[t * NSAE + perm[i]] = i & (NSAE - 1);
    }
}

// ---------------- sparse decode + SSE partials (t-major grid) ----------------
__global__ __launch_bounds__(256) void decode_kernel(
    const float* __restrict__ x,
    const int* __restrict__ tk_idx, const float* __restrict__ tk_val,
    const int* __restrict__ ipos,
    const float* __restrict__ Wd0, const float* __restrict__ bd0,
    const float* __restrict__ Wd1, const float* __restrict__ bd1,
    float* __restrict__ xhat, float* __restrict__ part0, float* __restrict__ part1)
{
    const int gbid = blockIdx.x;
    const int t = gbid >> 10;
    const int b = gbid & (NB - 1);
    const int bt = b * NT + t;
    const int tid = threadIdx.x;

    __shared__ int s_p[NK];
    __shared__ float s_v[NK];
    if (tid < NK) {
        const int s = tk_idx[b * NK + tid];
        s_v[tid] = tk_val[b * NK + tid];
        s_p[tid] = ipos[t * NSAE + s];
    }
    __syncthreads();

    float acc0[3], acc1[3];
#pragma unroll
    for (int r = 0; r < 3; ++r) {
        const int d = tid + 256 * r;
        acc0[r] = bd0[t * NDIN + d];
        acc1[r] = bd1[t * NDIN + d];
    }
    for (int j = 0; j < NK; ++j) {
        const int p = s_p[j];
        const float v = s_v[j];
        const float* w1 = Wd1 + ((size_t)p * NT + t) * NDIN;
#pragma unroll
        for (int r = 0; r < 3; ++r) acc1[r] = fmaf(v, w1[tid + 256 * r], acc1[r]);
        if (p < PFX0) {
            const float* w0 = Wd0 + ((size_t)p * NT + t) * NDIN;
#pragma unroll
            for (int r = 0; r < 3; ++r) acc0[r] = fmaf(v, w0[tid + 256 * r], acc0[r]);
        }
    }

    float e0 = 0.f, e1 = 0.f;
#pragma unroll
    for (int r = 0; r < 3; ++r) {
        const int d = tid + 256 * r;
        const float xv = x[(size_t)bt * NDIN + d];
        const float d0 = acc0[r] - xv;
        const float d1 = acc1[r] - xv;
        e0 = fmaf(d0, d0, e0);
        e1 = fmaf(d1, d1, e1);
        xhat[(size_t)bt * NDIN + d] = acc1[r];
    }

    __shared__ float r0[256];
    __shared__ float r1[256];
    r0[tid] = e0; r1[tid] = e1;
    __syncthreads();
    for (int w = 128; w > 0; w >>= 1) {
        if (tid < w) { r0[tid] += r0[tid + w]; r1[tid] += r1[tid + w]; }
        __syncthreads();
    }
    if (tid == 0) { part0[bt] = r0[0]; part1[bt] = r1[0]; }
}

// ---------------- final deterministic loss reduce ----------------
__global__ __launch_bounds__(256) void reduce_kernel(
    const float* __restrict__ part0, const float* __restrict__ part1,
    float* __restrict__ out_total)
{
    __shared__ double red[256];
    const int tid = threadIdx.x;
    double s = 0.0;
    for (int i = tid; i < NB * NT; i += 256)
        s += (double)part0[i] + (double)part1[i];
    red[tid] = s;
    __syncthreads();
    for (int w = 128; w > 0; w >>= 1) {
        if (tid < w) red[tid] += red[tid + w];
        __syncthreads();
    }
    if (tid == 0) out_total[0] = (float)(red[0] / ((double)NB * (double)(NT * 2)));
}

extern "C" void kernel_launch(void* const* d_in, const int* in_sizes, int n_in,
                              void* d_out, int out_size, void* d_ws, size_t ws_size,
                              hipStream_t stream)
{
    const float* x     = (const float*)d_in[0];
    const float* W_enc = (const float*)d_in[1];
    const float* b_enc = (const float*)d_in[2];
    const float* Wd0   = (const float*)d_in[3];
    const float* bd0   = (const float*)d_in[4];
    const float* Wd1   = (const float*)d_in[5];
    const float* bd1   = (const float*)d_in[6];
    const int*   perm  = (const int*)d_in[7];

    float* out       = (float*)d_out;
    float* out_total = out;
    float* out_xhat  = out + 1;
    float* out_z     = out + 1 + (size_t)NB * NT * NDIN;

    char* ws = (char*)d_ws;
    size_t off = 0;
    float* pre = (float*)(ws + off); off += (size_t)NB * NSAE * sizeof(float);

    const size_t szA2 = (size_t)NB * VKD * sizeof(_Float16);     // 12.6 MB
    _Float16* A2 = (_Float16*)(ws + off);
    const size_t off_splits_end = off + szA2;

    const bool fast = (ws_size >= off_splits_end +
        ((size_t)NB * NK * 8 + (size_t)NT * NSAE * 4 + (size_t)NB * NT * 8));
    size_t tail = fast ? off_splits_end : off;
    int*   tk_idx = (int*)(ws + tail);   tail += (size_t)NB * NK * sizeof(int);
    float* tk_val = (float*)(ws + tail); tail += (size_t)NB * NK * sizeof(float);
    int*   ipos   = (int*)(ws + tail);   tail += (size_t)NT * NSAE * sizeof(int);
    float* part0  = (float*)(ws + tail); tail += (size_t)NB * NT * sizeof(float);
    float* part1  = (float*)(ws + tail);

    if (fast) {
        conv_a_kernel<<<(NB * KDIM) / (256 * 4), 256, 0, stream>>>(x, A2);
        gemm_f16split_kernel<<<256, 512, 0, stream>>>(A2, W_enc, b_enc, pre);
    } else {
        gemm_pre_kernel<<<dim3(NSAE / 128, NB / 128), 256, 0, stream>>>(x, W_enc, b_enc, pre);
    }
    invperm_kernel<<<(NT * NSAE) / 256, 256, 0, stream>>>(perm, ipos);
    topk_kernel<<<NB, 256, 0, stream>>>(pre, tk_idx, tk_val, out_z);
    decode_kernel<<<NB * NT, 256, 0, stream>>>(x, tk_idx, tk_val, ipos,
                                               Wd0, bd0, Wd1, bd1,
                                               out_xhat, part0, part1);
    reduce_kernel<<<1, 256, 0, stream>>>(part0, part1, out_total);
}

// Round 14
// 577.533 us; speedup vs baseline: 1.4786x; 1.4786x over previous
//
// R12: convert∥MFMA overlap, spill-free. LDS 160KB: sA dbuf 64K + sBf 32K +
// sB32 dbuf 64K. Per step: read bf(32reg) -> bar -> {ld16 A(kt+1)->sA[flip],
// B32(kt+2)->sB32[kt&1]} + CONVERT(kt+1)->sBf + MFMA (af streamed per m-half
// from sA[kt&1], 16reg live) -> lgkm(0) vmcnt(0) bar. 2 waves/SIMD interleave
// convert with MFMA. Reg budget ~240/256 (R10 shape). Math bit-identical.
// Everything outside gemm identical to R10 (passed, 566us, 0.03125).
#include <hip/hip_runtime.h>
#include <hip/hip_bf16.h>
#include <stdint.h>

#define NB    1024
#define NT    4
#define NDIN  768
#define NSAE  16384
#define NK    64
#define KDIM  3072
#define PFX0  8192
#define KT96  96          // K-steps of 32 real K
#define VKD   6144        // virtual K per row of A2 (2*KDIM)

typedef _Float16 f16x8 __attribute__((ext_vector_type(8)));
typedef _Float16 f16x4 __attribute__((ext_vector_type(4)));
typedef float    f32x4 __attribute__((ext_vector_type(4)));

__device__ __forceinline__ unsigned f2key(float f) {
    union { float f; unsigned u; } cv; cv.f = f;
    unsigned u = cv.u;
    return u ^ ((unsigned)((int)u >> 31) | 0x80000000u);  // monotonic float->uint
}

__device__ __forceinline__ void ld16(const void* g, void* l) {
    __builtin_amdgcn_global_load_lds(
        (const __attribute__((address_space(1))) void*)g,
        (__attribute__((address_space(3))) void*)l, 16, 0, 0);
}

// ---------------- A split conversion (interleaved layout) ----------------
__global__ __launch_bounds__(256) void conv_a_kernel(
    const float* __restrict__ A, _Float16* __restrict__ A2)
{
    const int gid = blockIdx.x * 256 + threadIdx.x;
    const int m = gid / (KDIM / 4);
    const int k = (gid % (KDIM / 4)) * 4;
    const float4 v = *(const float4*)(A + (size_t)m * KDIM + k);
    const float vv[4] = { v.x, v.y, v.z, v.w };
    f16x4 h, l;
#pragma unroll
    for (int j = 0; j < 4; ++j) {
        const float sv = vv[j] * 64.f;
        const _Float16 hh = (_Float16)sv;
        h[j] = hh;
        l[j] = (_Float16)(sv - (float)hh);      // unboosted
    }
    const size_t ob = (size_t)m * VKD + (k >> 5) * 64 + (k & 31);
    *(f16x4*)(A2 + ob)      = h;
    *(f16x4*)(A2 + ob + 32) = l;
}

// ---------------- MFMA GEMM: pre = (A @ B) + bias, emulated f32 ----------------
__global__ __launch_bounds__(512, 1) void gemm_f16split_kernel(
    const _Float16* __restrict__ A2, const float* __restrict__ Bsrc,
    const float* __restrict__ bias, float* __restrict__ pre)
{
    __shared__ _Float16 sA[2 * 256 * 64];    // 64KB dbuf
    __shared__ _Float16 sBf[256 * 64];       // 32KB single
    __shared__ float    sB32[2 * 32 * 256];  // 64KB dbuf  (total 160KB)
    const int tid = threadIdx.x;
    const int lane = tid & 63;
    const int wid = tid >> 6;     // 0..7
    const int wm = wid >> 2;      // 0..1  (M half)
    const int wn = wid & 3;       // 0..3  (N quarter)

    // T1 chunked XCD swizzle: 256 blocks, bijective.
    const int bid = blockIdx.x;
    const int swz = (bid & 7) * 32 + (bid >> 3);
    const int m0 = (swz & 3) * 256;
    const int n0 = (swz >> 2) * 256;

    // staging pointers; LDS dest linear (ld16 HW constraint).
    const _Float16* pa[4]; const float* pb[4];
    _Float16* da[4]; float* db[4];
#pragma unroll
    for (int r = 0; r < 4; ++r) {
        const int d = tid + r * 512;
        const int rowA = d >> 3;
        const int lsA = (d & 7) ^ (rowA & 7);
        pa[r] = A2 + (size_t)(m0 + rowA) * VKD + lsA * 8;
        da[r] = sA + d * 8;                   // buf0; buf1 = +16384 f16
        const int kB = d >> 6;
        const int slotB = d & 63;
        pb[r] = Bsrc + (size_t)kB * NSAE + n0 + slotB * 4;
        db[r] = sB32 + d * 4;                 // buf0; buf1 = +8192 f32
    }

    // fragment read offsets (XOR-8 swizzled)
    const int rl = lane & 15;
    const int qw = lane >> 4;
    const int off0 = ((0 + qw) ^ (rl & 7)) * 8 + rl * 64;   // hi limb
    const int off1 = ((4 + qw) ^ (rl & 7)) * 8 + rl * 64;   // lo limb

    // convert-phase mapping (identical math to R10)
    const int cvn = tid & 255;
    const int cvkh = tid >> 8;
    const int cvsw = cvn & 7;
    _Float16* const cvout = sBf + cvn * 64;

#define CONVERT(half)                                                         \
    {                                                                         \
        const int cvb = (half) * 8192;                                        \
        float v[16];                                                          \
        _Pragma("unroll")                                                     \
        for (int j = 0; j < 16; ++j)                                          \
            v[j] = sB32[cvb + (cvkh * 16 + j) * 256 + cvn];                   \
        f16x8 h0{}, h1{}, l0{}, l1{};                                         \
        _Pragma("unroll")                                                     \
        for (int j = 0; j < 8; ++j) {                                         \
            const float sv = v[j] * 64.f;                                     \
            const _Float16 hh = (_Float16)sv;                                 \
            h0[j] = hh;                                                       \
            l0[j] = (_Float16)(sv - (float)hh);                               \
        }                                                                     \
        _Pragma("unroll")                                                     \
        for (int j = 0; j < 8; ++j) {                                         \
            const float sv = v[8 + j] * 64.f;                                 \
            const _Float16 hh = (_Float16)sv;                                 \
            h1[j] = hh;                                                       \
            l1[j] = (_Float16)(sv - (float)hh);                               \
        }                                                                     \
        *(f16x8*)(cvout + (((cvkh * 2 + 0) ^ cvsw) * 8)) = h0;                \
        *(f16x8*)(cvout + (((cvkh * 2 + 1) ^ cvsw) * 8)) = h1;                \
        *(f16x8*)(cvout + (((4 + cvkh * 2 + 0) ^ cvsw) * 8)) = l0;            \
        *(f16x8*)(cvout + (((4 + cvkh * 2 + 1) ^ cvsw) * 8)) = l1;            \
    }

    f32x4 acc[8][4];
#pragma unroll
    for (int mi = 0; mi < 8; ++mi)
#pragma unroll
        for (int ni = 0; ni < 4; ++ni)
            acc[mi][ni] = (f32x4){0.f, 0.f, 0.f, 0.f};

    const size_t KSTRB = (size_t)32 * NSAE;

    // prologue: A(0)->sA[0], B32(0)->buf0, B32(1)->buf1; convert Bf(0)
#pragma unroll
    for (int r = 0; r < 4; ++r) {
        ld16(pa[r], da[r]);
        ld16(pb[r], db[r]);
        ld16(pb[r] + KSTRB, db[r] + 8192);
    }
    asm volatile("s_waitcnt vmcnt(0)" ::: "memory");
    __builtin_amdgcn_sched_barrier(0);
    __builtin_amdgcn_s_barrier();
    __builtin_amdgcn_sched_barrier(0);
    CONVERT(0)                                  // reads sB32[0] -> writes sBf
    asm volatile("s_waitcnt lgkmcnt(0)" ::: "memory");
    __builtin_amdgcn_sched_barrier(0);
    __builtin_amdgcn_s_barrier();
    __builtin_amdgcn_sched_barrier(0);

    for (int kt = 0; kt < KT96; ++kt) {
        const int cbA = (kt & 1) ? 16384 : 0;   // current sA buf (f16 elems)
        const int nbA = cbA ^ 16384;

        // ===== phase 1: B fragments -> registers (consumes sBf) =====
        f16x8 bf[4][2];
#pragma unroll
        for (int ni = 0; ni < 4; ++ni) {
            const int rb = (wn * 64 + ni * 16) * 64;
            bf[ni][0] = *(const f16x8*)(sBf + rb + off0);
            bf[ni][1] = *(const f16x8*)(sBf + rb + off1);
        }
        asm volatile("s_waitcnt lgkmcnt(0)" ::: "memory");
        __builtin_amdgcn_sched_barrier(0);
        __builtin_amdgcn_s_barrier();            // sBf consumed everywhere
        __builtin_amdgcn_sched_barrier(0);

        // ===== phase 2: issue next-tile loads (land under MFMA) =====
        if (kt + 1 < KT96) {
            const int koA = (kt + 1) * 64;
#pragma unroll
            for (int r = 0; r < 4; ++r) ld16(pa[r] + koA, da[r] + nbA);
        }
        if (kt + 2 < KT96) {
            const size_t koB = (size_t)(kt + 2) * KSTRB;
            const int bb = (kt & 1) * 8192;      // (kt+2)&1 == kt&1
#pragma unroll
            for (int r = 0; r < 4; ++r) ld16(pb[r] + koB, db[r] + bb);
        }

        // ===== phase 3: convert Bf(kt+1) — overlaps MFMA via wave interleave =====
        if (kt + 1 < KT96) CONVERT((kt + 1) & 1)   // reads sB32[(kt+1)&1]

        // ===== phase 4: MFMA, af streamed per m-half from sA[cur] =====
        __builtin_amdgcn_s_setprio(1);
#pragma unroll
        for (int h = 0; h < 2; ++h) {
            f16x8 af[4][2];
#pragma unroll
            for (int i = 0; i < 4; ++i) {
                const int ra = cbA + (wm * 128 + (h * 4 + i) * 16) * 64;
                af[i][0] = *(const f16x8*)(sA + ra + off0);
                af[i][1] = *(const f16x8*)(sA + ra + off1);
            }
#pragma unroll
            for (int i = 0; i < 4; ++i)
#pragma unroll
                for (int ni = 0; ni < 4; ++ni) {
                    acc[h * 4 + i][ni] = __builtin_amdgcn_mfma_f32_16x16x32_f16(af[i][0], bf[ni][0], acc[h * 4 + i][ni], 0, 0, 0);
                    acc[h * 4 + i][ni] = __builtin_amdgcn_mfma_f32_16x16x32_f16(af[i][0], bf[ni][1], acc[h * 4 + i][ni], 0, 0, 0);
                    acc[h * 4 + i][ni] = __builtin_amdgcn_mfma_f32_16x16x32_f16(af[i][1], bf[ni][0], acc[h * 4 + i][ni], 0, 0, 0);
                }
        }
        __builtin_amdgcn_s_setprio(0);

        // ===== phase 5: drain & flip =====
        __builtin_amdgcn_sched_barrier(0);
        asm volatile("s_waitcnt lgkmcnt(0)" ::: "memory");   // convert writes + af reads done
        asm volatile("s_waitcnt vmcnt(0)" ::: "memory");     // A(kt+1) + B32(kt+2) landed
        __builtin_amdgcn_sched_barrier(0);
        __builtin_amdgcn_s_barrier();
        __builtin_amdgcn_sched_barrier(0);
    }
#undef CONVERT

    // epilogue: pre = acc*2^-12 + bias
    const float c12 = 1.0f / 4096.0f;
    float bv[4];
#pragma unroll
    for (int ni = 0; ni < 4; ++ni) bv[ni] = bias[n0 + wn * 64 + ni * 16 + rl];
#pragma unroll
    for (int mi = 0; mi < 8; ++mi)
#pragma unroll
        for (int ni = 0; ni < 4; ++ni)
#pragma unroll
            for (int r = 0; r < 4; ++r) {
                const int row = m0 + wm * 128 + mi * 16 + qw * 4 + r;
                const int col = n0 + wn * 64 + ni * 16 + rl;
                pre[(size_t)row * NSAE + col] = acc[mi][ni][r] * c12 + bv[ni];
            }
}

// ---------------- f32 fallback GEMM (R1, known-good) ----------------
__global__ __launch_bounds__(256) void gemm_pre_kernel(
    const float* __restrict__ A, const float* __restrict__ Bm,
    const float* __restrict__ bias, float* __restrict__ pre)
{
    __shared__ float As[16][128];
    __shared__ float Bs[16][128];
    const int bn = blockIdx.x * 128;
    const int bm = blockIdx.y * 128;
    const int tid = threadIdx.x;
    const int tx = tid & 15;
    const int ty = tid >> 4;

    float acc[8][8];
#pragma unroll
    for (int i = 0; i < 8; ++i)
#pragma unroll
        for (int j = 0; j < 8; ++j) acc[i][j] = 0.f;

    for (int k0 = 0; k0 < KDIM; k0 += 16) {
#pragma unroll
        for (int i = 0; i < 2; ++i) {
            const int idx = i * 256 + tid;
            const int r = idx >> 2;
            const int c = (idx & 3) << 2;
            const float4 v = *(const float4*)(A + (size_t)(bm + r) * KDIM + (k0 + c));
            As[c + 0][r] = v.x; As[c + 1][r] = v.y;
            As[c + 2][r] = v.z; As[c + 3][r] = v.w;
        }
#pragma unroll
        for (int i = 0; i < 2; ++i) {
            const int idx = i * 256 + tid;
            const int r = idx >> 5;
            const int c = (idx & 31) << 2;
            *(float4*)(&Bs[r][c]) = *(const float4*)(Bm + (size_t)(k0 + r) * NSAE + (bn + c));
        }
        __syncthreads();
#pragma unroll
        for (int kk = 0; kk < 16; ++kk) {
            const float4 a0 = *(const float4*)(&As[kk][ty * 8]);
            const float4 a1 = *(const float4*)(&As[kk][ty * 8 + 4]);
            const float4 b0 = *(const float4*)(&Bs[kk][tx * 8]);
            const float4 b1 = *(const float4*)(&Bs[kk][tx * 8 + 4]);
            const float av[8] = { a0.x, a0.y, a0.z, a0.w, a1.x, a1.y, a1.z, a1.w };
            const float bv[8] = { b0.x, b0.y, b0.z, b0.w, b1.x, b1.y, b1.z, b1.w };
#pragma unroll
            for (int i = 0; i < 8; ++i)
#pragma unroll
                for (int j = 0; j < 8; ++j)
                    acc[i][j] = fmaf(av[i], bv[j], acc[i][j]);
        }
        __syncthreads();
    }

    float bv8[8];
#pragma unroll
    for (int j = 0; j < 8; ++j) bv8[j] = bias[bn + tx * 8 + j];
#pragma unroll
    for (int i = 0; i < 8; ++i) {
        float4 o0, o1;
        o0.x = acc[i][0] + bv8[0]; o0.y = acc[i][1] + bv8[1];
        o0.z = acc[i][2] + bv8[2]; o0.w = acc[i][3] + bv8[3];
        o1.x = acc[i][4] + bv8[4]; o1.y = acc[i][5] + bv8[5];
        o1.z = acc[i][6] + bv8[6]; o1.w = acc[i][7] + bv8[7];
        const size_t off = (size_t)(bm + ty * 8 + i) * NSAE + bn + tx * 8;
        *(float4*)(pre + off) = o0;
        *(float4*)(pre + off + 4) = o1;
    }
}

// ---------------- per-row radix top-64, row held in registers ----------------
__global__ __launch_bounds__(256) void topk_kernel(
    const float* __restrict__ pre,
    int* __restrict__ tk_idx, float* __restrict__ tk_val,
    float* __restrict__ z)
{
    __shared__ unsigned hist[4][256];
    __shared__ int sel[NK];
    __shared__ float sval[NK];
    __shared__ int ties[256];
    __shared__ float tval[256];
    __shared__ unsigned sh_prefix, sh_want, sh_cnt, sh_tiecnt;

    const int b = blockIdx.x;
    const int tid = threadIdx.x;
    const int w = tid >> 6;
    const float* row = pre + (size_t)b * NSAE;
    float* zrow = z + (size_t)b * NSAE;

    if (tid == 0) { sh_prefix = 0u; sh_want = NK; sh_cnt = 0u; sh_tiecnt = 0u; }
    hist[0][tid] = 0u; hist[1][tid] = 0u; hist[2][tid] = 0u; hist[3][tid] = 0u;
    __syncthreads();

    float4 rv[16];
#pragma unroll
    for (int j = 0; j < 16; ++j) {
        const int i = tid * 4 + j * 1024;
        rv[j] = *(const float4*)(row + i);
        *(float4*)(zrow + i) = make_float4(0.f, 0.f, 0.f, 0.f);
        atomicAdd(&hist[w][f2key(rv[j].x) >> 24], 1u);
        atomicAdd(&hist[w][f2key(rv[j].y) >> 24], 1u);
        atomicAdd(&hist[w][f2key(rv[j].z) >> 24], 1u);
        atomicAdd(&hist[w][f2key(rv[j].w) >> 24], 1u);
    }
    __syncthreads();
    hist[0][tid] += hist[1][tid] + hist[2][tid] + hist[3][tid];
    __syncthreads();
    if (tid == 0) {
        unsigned cum = 0u; int bsel = 0;
        for (int bin = 255; bin >= 0; --bin) {
            const unsigned c = hist[0][bin];
            if (cum + c >= NK) { bsel = bin; break; }
            cum += c;
        }
        sh_prefix = ((unsigned)bsel << 24);
        sh_want = NK - cum;
    }
    __syncthreads();

    for (int pass = 1; pass < 4; ++pass) {
        hist[0][tid] = 0u; hist[1][tid] = 0u; hist[2][tid] = 0u; hist[3][tid] = 0u;
        __syncthreads();
        const int shift = 24 - pass * 8;
        const unsigned mask = 0xFFFFFFFFu << (shift + 8);
        const unsigned pfx = sh_prefix;
#pragma unroll
        for (int j = 0; j < 16; ++j) {
            const float fv[4] = { rv[j].x, rv[j].y, rv[j].z, rv[j].w };
#pragma unroll
            for (int q = 0; q < 4; ++q) {
                const unsigned k = f2key(fv[q]);
                if ((k & mask) == pfx) atomicAdd(&hist[w][(k >> shift) & 0xFFu], 1u);
            }
        }
        __syncthreads();
        hist[0][tid] += hist[1][tid] + hist[2][tid] + hist[3][tid];
        __syncthreads();
        if (tid == 0) {
            const unsigned want = sh_want;
            unsigned cum = 0u; int bsel = 0;
            for (int bin = 255; bin >= 0; --bin) {
                const unsigned c = hist[0][bin];
                if (cum + c >= want) { bsel = bin; break; }
                cum += c;
            }
            sh_prefix |= ((unsigned)bsel << shift);
            sh_want = want - cum;
        }
        __syncthreads();
    }

    const unsigned T = sh_prefix;
#pragma unroll
    for (int j = 0; j < 16; ++j) {
        const float fv[4] = { rv[j].x, rv[j].y, rv[j].z, rv[j].w };
#pragma unroll
        for (int q = 0; q < 4; ++q) {
            const unsigned k = f2key(fv[q]);
            if (k > T) {
                const unsigned s = atomicAdd(&sh_cnt, 1u);
                sel[s] = tid * 4 + j * 1024 + q;
                sval[s] = fv[q];
            } else if (k == T) {
                const unsigned s = atomicAdd(&sh_tiecnt, 1u);
                if (s < 256u) { ties[s] = tid * 4 + j * 1024 + q; tval[s] = fv[q]; }
            }
        }
    }
    __syncthreads();
    if (tid == 0) {
        const unsigned tc = sh_tiecnt;
        const int n = (int)(tc < 256u ? tc : 256u);
        for (int a = 1; a < n; ++a) {
            const int v = ties[a]; const float fv = tval[a]; int c = a;
            while (c > 0 && ties[c - 1] > v) {
                ties[c] = ties[c - 1]; tval[c] = tval[c - 1]; --c;
            }
            ties[c] = v; tval[c] = fv;
        }
        const int base = (int)sh_cnt;
        const int want = (int)sh_want;
        for (int j = 0; j < want && j < n; ++j) {
            sel[base + j] = ties[j]; sval[base + j] = tval[j];
        }
    }
    __syncthreads();
    if (tid < NK) {
        const int myi = sel[tid];
        int rank = 0;
#pragma unroll 1
        for (int j = 0; j < NK; ++j) rank += (sel[j] < myi) ? 1 : 0;
        const float v = fmaxf(sval[tid], 0.f);
        tk_idx[b * NK + rank] = myi;
        tk_val[b * NK + rank] = v;
        zrow[myi] = v;
    }
}

// ---------------- inverse permutation ----------------
__global__ __launch_bounds__(256) void invperm_kernel(
    const int* __restrict__ perm, int* __restrict__ ipos)
{
    const int i = blockIdx.x * 256 + threadIdx.x;
    if (i < NT * NSAE) {
        const int t = i >> 14;
        ipos[t * NSAE + perm[i]] = i & (NSAE - 1);
    }
}

// ---------------- sparse decode + SSE partials (t-major grid) ----------------
__global__ __launch_bounds__(256) void decode_kernel(
    const float* __restrict__ x,
    const int* __restrict__ tk_idx, const float* __restrict__ tk_val,
    const int* __restrict__ ipos,
    const float* __restrict__ Wd0, const float* __restrict__ bd0,
    const float* __restrict__ Wd1, const float* __restrict__ bd1,
    float* __restrict__ xhat, float* __restrict__ part0, float* __restrict__ part1)
{
    const int gbid = blockIdx.x;
    const int t = gbid >> 10;
    const int b = gbid & (NB - 1);
    const int bt = b * NT + t;
    const int tid = threadIdx.x;

    __shared__ int s_p[NK];
    __shared__ float s_v[NK];
    if (tid < NK) {
        const int s = tk_idx[b * NK + tid];
        s_v[tid] = tk_val[b * NK + tid];
        s_p[tid] = ipos[t * NSAE + s];
    }
    __syncthreads();

    float acc0[3], acc1[3];
#pragma unroll
    for (int r = 0; r < 3; ++r) {
        const int d = tid + 256 * r;
        acc0[r] = bd0[t * NDIN + d];
        acc1[r] = bd1[t * NDIN + d];
    }
    for (int j = 0; j < NK; ++j) {
        const int p = s_p[j];
        const float v = s_v[j];
        const float* w1 = Wd1 + ((size_t)p * NT + t) * NDIN;
#pragma unroll
        for (int r = 0; r < 3; ++r) acc1[r] = fmaf(v, w1[tid + 256 * r], acc1[r]);
        if (p < PFX0) {
            const float* w0 = Wd0 + ((size_t)p * NT + t) * NDIN;
#pragma unroll
            for (int r = 0; r < 3; ++r) acc0[r] = fmaf(v, w0[tid + 256 * r], acc0[r]);
        }
    }

    float e0 = 0.f, e1 = 0.f;
#pragma unroll
    for (int r = 0; r < 3; ++r) {
        const int d = tid + 256 * r;
        const float xv = x[(size_t)bt * NDIN + d];
        const float d0 = acc0[r] - xv;
        const float d1 = acc1[r] - xv;
        e0 = fmaf(d0, d0, e0);
        e1 = fmaf(d1, d1, e1);
        xhat[(size_t)bt * NDIN + d] = acc1[r];
    }

    __shared__ float r0[256];
    __shared__ float r1[256];
    r0[tid] = e0; r1[tid] = e1;
    __syncthreads();
    for (int w = 128; w > 0; w >>= 1) {
        if (tid < w) { r0[tid] += r0[tid + w]; r1[tid] += r1[tid + w]; }
        __syncthreads();
    }
    if (tid == 0) { part0[bt] = r0[0]; part1[bt] = r1[0]; }
}

// ---------------- final deterministic loss reduce ----------------
__global__ __launch_bounds__(256) void reduce_kernel(
    const float* __restrict__ part0, const float* __restrict__ part1,
    float* __restrict__ out_total)
{
    __shared__ double red[256];
    const int tid = threadIdx.x;
    double s = 0.0;
    for (int i = tid; i < NB * NT; i += 256)
        s += (double)part0[i] + (double)part1[i];
    red[tid] = s;
    __syncthreads();
    for (int w = 128; w > 0; w >>= 1) {
        if (tid < w) red[tid] += red[tid + w];
        __syncthreads();
    }
    if (tid == 0) out_total[0] = (float)(red[0] / ((double)NB * (double)(NT * 2)));
}

extern "C" void kernel_launch(void* const* d_in, const int* in_sizes, int n_in,
                              void* d_out, int out_size, void* d_ws, size_t ws_size,
                              hipStream_t stream)
{
    const float* x     = (const float*)d_in[0];
    const float* W_enc = (const float*)d_in[1];
    const float* b_enc = (const float*)d_in[2];
    const float* Wd0   = (const float*)d_in[3];
    const float* bd0   = (const float*)d_in[4];
    const float* Wd1   = (const float*)d_in[5];
    const float* bd1   = (const float*)d_in[6];
    const int*   perm  = (const int*)d_in[7];

    float* out       = (float*)d_out;
    float* out_total = out;
    float* out_xhat  = out + 1;
    float* out_z     = out + 1 + (size_t)NB * NT * NDIN;

    char* ws = (char*)d_ws;
    size_t off = 0;
    float* pre = (float*)(ws + off); off += (size_t)NB * NSAE * sizeof(float);

    const size_t szA2 = (size_t)NB * VKD * sizeof(_Float16);     // 12.6 MB
    _Float16* A2 = (_Float16*)(ws + off);
    const size_t off_splits_end = off + szA2;

    const bool fast = (ws_size >= off_splits_end +
        ((size_t)NB * NK * 8 + (size_t)NT * NSAE * 4 + (size_t)NB * NT * 8));
    size_t tail = fast ? off_splits_end : off;
    int*   tk_idx = (int*)(ws + tail);   tail += (size_t)NB * NK * sizeof(int);
    float* tk_val = (float*)(ws + tail); tail += (size_t)NB * NK * sizeof(float);
    int*   ipos   = (int*)(ws + tail);   tail += (size_t)NT * NSAE * sizeof(int);
    float* part0  = (float*)(ws + tail); tail += (size_t)NB * NT * sizeof(float);
    float* part1  = (float*)(ws + tail);

    if (fast) {
        conv_a_kernel<<<(NB * KDIM) / (256 * 4), 256, 0, stream>>>(x, A2);
        gemm_f16split_kernel<<<256, 512, 0, stream>>>(A2, W_enc, b_enc, pre);
    } else {
        gemm_pre_kernel<<<dim3(NSAE / 128, NB / 128), 256, 0, stream>>>(x, W_enc, b_enc, pre);
    }
    invperm_kernel<<<(NT * NSAE) / 256, 256, 0, stream>>>(perm, ipos);
    topk_kernel<<<NB, 256, 0, stream>>>(pre, tk_idx, tk_val, out_z);
    decode_kernel<<<NB * NT, 256, 0, stream>>>(x, tk_idx, tk_val, ipos,
                                               Wd0, bd0, Wd1, bd1,
                                               out_xhat, part0, part1);
    reduce_kernel<<<1, 256, 0, stream>>>(part0, part1, out_total);
}

// Round 15
// 524.671 us; speedup vs baseline: 1.6275x; 1.1008x over previous
//
// R13: best-known config. GEMM = R10 exact (fused B convert phase, 128KB LDS,
// 2-barrier, measured 340us/total 566). topk upgraded: parallel suffix-scan
// bin pick + candidate-collection after pass 0 (~400 of 16384), passes 1-3 and
// final over candidates only. Exactness preserved (same keys/ties/ranks).
#include <hip/hip_runtime.h>
#include <hip/hip_bf16.h>
#include <stdint.h>

#define NB    1024
#define NT    4
#define NDIN  768
#define NSAE  16384
#define NK    64
#define KDIM  3072
#define PFX0  8192
#define KT96  96          // K-steps of 32 real K
#define VKD   6144        // virtual K per row of A2 (2*KDIM)
#define CCAP  2048        // topk candidate cap (expected ~400, 80+ sigma)

typedef _Float16 f16x8 __attribute__((ext_vector_type(8)));
typedef _Float16 f16x4 __attribute__((ext_vector_type(4)));
typedef float    f32x4 __attribute__((ext_vector_type(4)));

__device__ __forceinline__ unsigned f2key(float f) {
    union { float f; unsigned u; } cv; cv.f = f;
    unsigned u = cv.u;
    return u ^ ((unsigned)((int)u >> 31) | 0x80000000u);  // monotonic float->uint
}

__device__ __forceinline__ void ld16(const void* g, void* l) {
    __builtin_amdgcn_global_load_lds(
        (const __attribute__((address_space(1))) void*)g,
        (__attribute__((address_space(3))) void*)l, 16, 0, 0);
}

// ---------------- A split conversion (interleaved layout) ----------------
// sv = v*64; hi = fp16(sv); lo = fp16(sv - hi)  [unboosted, same scale].
__global__ __launch_bounds__(256) void conv_a_kernel(
    const float* __restrict__ A, _Float16* __restrict__ A2)
{
    const int gid = blockIdx.x * 256 + threadIdx.x;
    const int m = gid / (KDIM / 4);
    const int k = (gid % (KDIM / 4)) * 4;
    const float4 v = *(const float4*)(A + (size_t)m * KDIM + k);
    const float vv[4] = { v.x, v.y, v.z, v.w };
    f16x4 h, l;
#pragma unroll
    for (int j = 0; j < 4; ++j) {
        const float sv = vv[j] * 64.f;
        const _Float16 hh = (_Float16)sv;
        h[j] = hh;
        l[j] = (_Float16)(sv - (float)hh);      // unboosted
    }
    const size_t ob = (size_t)m * VKD + (k >> 5) * 64 + (k & 31);
    *(f16x4*)(A2 + ob)      = h;
    *(f16x4*)(A2 + ob + 32) = l;
}

// ---------------- MFMA GEMM (R10 exact): pre = (A @ B) + bias ----------------
// 256x256 tile, 8 waves (2Mx4N).
// LDS: sA f16 dbuf [2][256][64] 64KB | sB32 f32 [32][256] 32KB | sBf f16
// [256][64] 32KB. Per K-step: {convert sB32->sBf} lgkm(0) bar ->
// {issue 8 ld16 (A->sA[nb], B->sB32); read frags b128; 96 MFMA} vmcnt(0) bar.
__global__ __launch_bounds__(512, 2) void gemm_f16split_kernel(
    const _Float16* __restrict__ A2, const float* __restrict__ Bsrc,
    const float* __restrict__ bias, float* __restrict__ pre)
{
    __shared__ _Float16 sA[2 * 256 * 64];   // 64KB dbuf
    __shared__ float    sB32[32 * 256];     // 32KB single
    __shared__ _Float16 sBf[256 * 64];      // 32KB single
    const int tid = threadIdx.x;
    const int lane = tid & 63;
    const int wid = tid >> 6;     // 0..7
    const int wm = wid >> 2;      // 0..1  (M half)
    const int wn = wid & 3;       // 0..3  (N quarter)

    // T1 chunked XCD swizzle: 256 blocks, 256%8==0 -> bijective.
    const int bid = blockIdx.x;
    const int swz = (bid & 7) * 32 + (bid >> 3);
    const int m0 = (swz & 3) * 256;
    const int n0 = (swz >> 2) * 256;

    // staging pointers. LDS dest linear (ld16 HW constraint).
    // A: global source carries inverse XOR-8 swizzle (G21). B: linear.
    const _Float16* pa[4]; const float* pb[4];
    _Float16* da[4]; float* db[4];
#pragma unroll
    for (int r = 0; r < 4; ++r) {
        const int d = tid + r * 512;          // 0..2047 (16B units)
        const int rowA = d >> 3;
        const int lsA = (d & 7) ^ (rowA & 7);
        pa[r] = A2 + (size_t)(m0 + rowA) * VKD + lsA * 8;
        da[r] = sA + d * 8;
        const int kB = d >> 6;                // 0..31
        const int slotB = d & 63;             // 16B slots within row
        pb[r] = Bsrc + (size_t)kB * NSAE + n0 + slotB * 4;
        db[r] = sB32 + d * 4;
    }

    // fragment read offsets (XOR-8 swizzled): slot' = (limb*4+qw) ^ (rl&7)
    const int rl = lane & 15;
    const int qw = lane >> 4;
    const int off0 = ((0 + qw) ^ (rl & 7)) * 8 + rl * 64;   // hi limb
    const int off1 = ((4 + qw) ^ (rl & 7)) * 8 + rl * 64;   // lo limb

    // convert-phase mapping: thread -> (n, khalf)
    const int cvn = tid & 255;
    const int cvkh = tid >> 8;                // 0 or 1
    const int cvsw = cvn & 7;
    _Float16* const cvout = sBf + cvn * 64;

    f32x4 acc[8][4];
#pragma unroll
    for (int mi = 0; mi < 8; ++mi)
#pragma unroll
        for (int ni = 0; ni < 4; ++ni)
            acc[mi][ni] = (f32x4){0.f, 0.f, 0.f, 0.f};

    // prologue: stage tile 0
#pragma unroll
    for (int r = 0; r < 4; ++r) { ld16(pa[r], da[r]); ld16(pb[r], db[r]); }
    asm volatile("s_waitcnt vmcnt(0)" ::: "memory");
    __builtin_amdgcn_sched_barrier(0);
    __builtin_amdgcn_s_barrier();
    __builtin_amdgcn_sched_barrier(0);

    const size_t KSTRB = (size_t)32 * NSAE;   // B f32 elements per K-step

    for (int kt = 0; kt < KT96; ++kt) {
        const int cbA = (kt & 1) ? 16384 : 0;
        const int nbA = cbA ^ 16384;

        // ===== convert phase: sB32 (tile kt, f32) -> sBf (hi/lo f16) =====
        {
            float v[16];
#pragma unroll
            for (int j = 0; j < 16; ++j)
                v[j] = sB32[(cvkh * 16 + j) * 256 + cvn];
            f16x8 h0{}, h1{}, l0{}, l1{};
#pragma unroll
            for (int j = 0; j < 8; ++j) {
                const float sv = v[j] * 64.f;
                const _Float16 hh = (_Float16)sv;
                h0[j] = hh;
                l0[j] = (_Float16)(sv - (float)hh);
            }
#pragma unroll
            for (int j = 0; j < 8; ++j) {
                const float sv = v[8 + j] * 64.f;
                const _Float16 hh = (_Float16)sv;
                h1[j] = hh;
                l1[j] = (_Float16)(sv - (float)hh);
            }
            *(f16x8*)(cvout + (((cvkh * 2 + 0) ^ cvsw) * 8)) = h0;
            *(f16x8*)(cvout + (((cvkh * 2 + 1) ^ cvsw) * 8)) = h1;
            *(f16x8*)(cvout + (((4 + cvkh * 2 + 0) ^ cvsw) * 8)) = l0;
            *(f16x8*)(cvout + (((4 + cvkh * 2 + 1) ^ cvsw) * 8)) = l1;
        }
        asm volatile("s_waitcnt lgkmcnt(0)" ::: "memory");
        __builtin_amdgcn_sched_barrier(0);
        __builtin_amdgcn_s_barrier();            // sBf ready; sB32 consumed
        __builtin_amdgcn_sched_barrier(0);

        // ===== compute phase: prefetch next tile + frag reads + 96 MFMA =====
        if (kt + 1 < KT96) {
            const int koA = (kt + 1) * 64;
            const size_t koB = (size_t)(kt + 1) * KSTRB;
#pragma unroll
            for (int r = 0; r < 4; ++r) {
                ld16(pa[r] + koA, da[r] + nbA);
                ld16(pb[r] + koB, db[r]);        // sB32 free to overwrite now
            }
        }
        __builtin_amdgcn_s_setprio(1);
        f16x8 bf[4][2];
#pragma unroll
        for (int ni = 0; ni < 4; ++ni) {
            const int rb = (wn * 64 + ni * 16) * 64;
            bf[ni][0] = *(const f16x8*)(sBf + rb + off0);
            bf[ni][1] = *(const f16x8*)(sBf + rb + off1);
        }
#pragma unroll
        for (int h = 0; h < 2; ++h) {
            f16x8 af[4][2];
#pragma unroll
            for (int i = 0; i < 4; ++i) {
                const int ra = cbA + (wm * 128 + (h * 4 + i) * 16) * 64;
                af[i][0] = *(const f16x8*)(sA + ra + off0);
                af[i][1] = *(const f16x8*)(sA + ra + off1);
            }
#pragma unroll
            for (int i = 0; i < 4; ++i)
#pragma unroll
                for (int ni = 0; ni < 4; ++ni) {
                    acc[h * 4 + i][ni] = __builtin_amdgcn_mfma_f32_16x16x32_f16(af[i][0], bf[ni][0], acc[h * 4 + i][ni], 0, 0, 0);
                    acc[h * 4 + i][ni] = __builtin_amdgcn_mfma_f32_16x16x32_f16(af[i][0], bf[ni][1], acc[h * 4 + i][ni], 0, 0, 0);
                    acc[h * 4 + i][ni] = __builtin_amdgcn_mfma_f32_16x16x32_f16(af[i][1], bf[ni][0], acc[h * 4 + i][ni], 0, 0, 0);
                }
        }
        __builtin_amdgcn_s_setprio(0);
        __builtin_amdgcn_sched_barrier(0);       // pin reads+MFMAs above drain
        asm volatile("s_waitcnt vmcnt(0)" ::: "memory");  // next tile landed
        __builtin_amdgcn_sched_barrier(0);
        __builtin_amdgcn_s_barrier();            // all waves done with sBf/sA[cb]
        __builtin_amdgcn_sched_barrier(0);
    }

    // epilogue: pre = acc*2^-12 + bias  (single scale: /(64*64))
    const float c12 = 1.0f / 4096.0f;
    float bv[4];
#pragma unroll
    for (int ni = 0; ni < 4; ++ni) bv[ni] = bias[n0 + wn * 64 + ni * 16 + rl];
#pragma unroll
    for (int mi = 0; mi < 8; ++mi)
#pragma unroll
        for (int ni = 0; ni < 4; ++ni)
#pragma unroll
            for (int r = 0; r < 4; ++r) {
                const int row = m0 + wm * 128 + mi * 16 + qw * 4 + r;
                const int col = n0 + wn * 64 + ni * 16 + rl;
                pre[(size_t)row * NSAE + col] = acc[mi][ni][r] * c12 + bv[ni];
            }
}

// ---------------- f32 fallback GEMM (R1, known-good) ----------------
__global__ __launch_bounds__(256) void gemm_pre_kernel(
    const float* __restrict__ A, const float* __restrict__ Bm,
    const float* __restrict__ bias, float* __restrict__ pre)
{
    __shared__ float As[16][128];
    __shared__ float Bs[16][128];
    const int bn = blockIdx.x * 128;
    const int bm = blockIdx.y * 128;
    const int tid = threadIdx.x;
    const int tx = tid & 15;
    const int ty = tid >> 4;

    float acc[8][8];
#pragma unroll
    for (int i = 0; i < 8; ++i)
#pragma unroll
        for (int j = 0; j < 8; ++j) acc[i][j] = 0.f;

    for (int k0 = 0; k0 < KDIM; k0 += 16) {
#pragma unroll
        for (int i = 0; i < 2; ++i) {
            const int idx = i * 256 + tid;
            const int r = idx >> 2;
            const int c = (idx & 3) << 2;
            const float4 v = *(const float4*)(A + (size_t)(bm + r) * KDIM + (k0 + c));
            As[c + 0][r] = v.x; As[c + 1][r] = v.y;
            As[c + 2][r] = v.z; As[c + 3][r] = v.w;
        }
#pragma unroll
        for (int i = 0; i < 2; ++i) {
            const int idx = i * 256 + tid;
            const int r = idx >> 5;
            const int c = (idx & 31) << 2;
            *(float4*)(&Bs[r][c]) = *(const float4*)(Bm + (size_t)(k0 + r) * NSAE + (bn + c));
        }
        __syncthreads();
#pragma unroll
        for (int kk = 0; kk < 16; ++kk) {
            const float4 a0 = *(const float4*)(&As[kk][ty * 8]);
            const float4 a1 = *(const float4*)(&As[kk][ty * 8 + 4]);
            const float4 b0 = *(const float4*)(&Bs[kk][tx * 8]);
            const float4 b1 = *(const float4*)(&Bs[kk][tx * 8 + 4]);
            const float av[8] = { a0.x, a0.y, a0.z, a0.w, a1.x, a1.y, a1.z, a1.w };
            const float bv[8] = { b0.x, b0.y, b0.z, b0.w, b1.x, b1.y, b1.z, b1.w };
#pragma unroll
            for (int i = 0; i < 8; ++i)
#pragma unroll
                for (int j = 0; j < 8; ++j)
                    acc[i][j] = fmaf(av[i], bv[j], acc[i][j]);
        }
        __syncthreads();
    }

    float bv8[8];
#pragma unroll
    for (int j = 0; j < 8; ++j) bv8[j] = bias[bn + tx * 8 + j];
#pragma unroll
    for (int i = 0; i < 8; ++i) {
        float4 o0, o1;
        o0.x = acc[i][0] + bv8[0]; o0.y = acc[i][1] + bv8[1];
        o0.z = acc[i][2] + bv8[2]; o0.w = acc[i][3] + bv8[3];
        o1.x = acc[i][4] + bv8[4]; o1.y = acc[i][5] + bv8[5];
        o1.z = acc[i][6] + bv8[6]; o1.w = acc[i][7] + bv8[7];
        const size_t off = (size_t)(bm + ty * 8 + i) * NSAE + bn + tx * 8;
        *(float4*)(pre + off) = o0;
        *(float4*)(pre + off + 4) = o1;
    }
}

// ---------------- per-row radix top-64 (candidate-collect version) ----------------
// pass 0: full hist (top byte) -> parallel suffix scan -> bsel0; collect
// candidates (top byte >= bsel0, ~400 expected) -> passes 1-3 + final over
// candidates only. Fallback to full scans if candidates overflow CCAP.
__global__ __launch_bounds__(256) void topk_kernel(
    const float* __restrict__ pre,
    int* __restrict__ tk_idx, float* __restrict__ tk_val,
    float* __restrict__ z)
{
    __shared__ unsigned hist[4][256];
    __shared__ unsigned scan[257];
    __shared__ int   cand[CCAP];
    __shared__ float cval[CCAP];
    __shared__ int sel[NK];
    __shared__ float sval[NK];
    __shared__ int ties[256];
    __shared__ float tval[256];
    __shared__ unsigned sh_prefix, sh_want, sh_cnt, sh_tiecnt, sh_ccnt, sh_bsel;

    const int b = blockIdx.x;
    const int tid = threadIdx.x;
    const int w = tid >> 6;
    const float* row = pre + (size_t)b * NSAE;
    float* zrow = z + (size_t)b * NSAE;

    if (tid == 0) { sh_cnt = 0u; sh_tiecnt = 0u; sh_ccnt = 0u; }
    hist[0][tid] = 0u; hist[1][tid] = 0u; hist[2][tid] = 0u; hist[3][tid] = 0u;
    __syncthreads();

    // load row (registers) + zero z + pass-0 histogram (top 8 bits)
    float4 rv[16];
#pragma unroll
    for (int j = 0; j < 16; ++j) {
        const int i = tid * 4 + j * 1024;
        rv[j] = *(const float4*)(row + i);
        *(float4*)(zrow + i) = make_float4(0.f, 0.f, 0.f, 0.f);
        atomicAdd(&hist[w][f2key(rv[j].x) >> 24], 1u);
        atomicAdd(&hist[w][f2key(rv[j].y) >> 24], 1u);
        atomicAdd(&hist[w][f2key(rv[j].z) >> 24], 1u);
        atomicAdd(&hist[w][f2key(rv[j].w) >> 24], 1u);
    }
    __syncthreads();
    hist[0][tid] += hist[1][tid] + hist[2][tid] + hist[3][tid];
    __syncthreads();

    // parallel inclusive suffix scan: scan[t] = sum_{b>=t} hist[b]
    scan[tid] = hist[0][tid];
    if (tid == 0) scan[256] = 0u;
    __syncthreads();
    for (int s = 1; s < 256; s <<= 1) {
        const unsigned v = (tid + s < 256) ? scan[tid + s] : 0u;
        __syncthreads();
        scan[tid] += v;
        __syncthreads();
    }
    // unique crossing: scan[t] >= 64 > scan[t+1]
    if (scan[tid] >= (unsigned)NK && scan[tid + 1] < (unsigned)NK) {
        sh_bsel = (unsigned)tid;
        sh_prefix = ((unsigned)tid << 24);
        sh_want = (unsigned)NK - scan[tid + 1];
    }
    __syncthreads();
    const unsigned bsel0 = sh_bsel;

    // collect candidates: top byte >= bsel0 (covers everything >= threshold bin)
#pragma unroll
    for (int j = 0; j < 16; ++j) {
        const float fv[4] = { rv[j].x, rv[j].y, rv[j].z, rv[j].w };
#pragma unroll
        for (int q = 0; q < 4; ++q) {
            const unsigned k = f2key(fv[q]);
            if ((k >> 24) >= bsel0) {
                const unsigned s = atomicAdd(&sh_ccnt, 1u);
                if (s < (unsigned)CCAP) {
                    cand[s] = tid * 4 + j * 1024 + q;
                    cval[s] = fv[q];
                }
            }
        }
    }
    __syncthreads();
    const int ccnt_raw = (int)sh_ccnt;
    const bool ovf = ccnt_raw > CCAP;           // ~80 sigma; fallback path
    const int ccnt = ovf ? 0 : ccnt_raw;

    for (int pass = 1; pass < 4; ++pass) {
        hist[0][tid] = 0u; hist[1][tid] = 0u; hist[2][tid] = 0u; hist[3][tid] = 0u;
        __syncthreads();
        const int shift = 24 - pass * 8;
        const unsigned mask = 0xFFFFFFFFu << (shift + 8);
        const unsigned pfx = sh_prefix;
        if (!ovf) {
            for (int i = tid; i < ccnt; i += 256) {
                const unsigned k = f2key(cval[i]);
                if ((k & mask) == pfx) atomicAdd(&hist[w][(k >> shift) & 0xFFu], 1u);
            }
        } else {
#pragma unroll
            for (int j = 0; j < 16; ++j) {
                const float fv[4] = { rv[j].x, rv[j].y, rv[j].z, rv[j].w };
#pragma unroll
                for (int q = 0; q < 4; ++q) {
                    const unsigned k = f2key(fv[q]);
                    if ((k & mask) == pfx) atomicAdd(&hist[w][(k >> shift) & 0xFFu], 1u);
                }
            }
        }
        __syncthreads();
        hist[0][tid] += hist[1][tid] + hist[2][tid] + hist[3][tid];
        __syncthreads();
        scan[tid] = hist[0][tid];
        if (tid == 0) scan[256] = 0u;
        __syncthreads();
        for (int s = 1; s < 256; s <<= 1) {
            const unsigned v = (tid + s < 256) ? scan[tid + s] : 0u;
            __syncthreads();
            scan[tid] += v;
            __syncthreads();
        }
        const unsigned want = sh_want;
        __syncthreads();                         // all read want before update
        if (scan[tid] >= want && scan[tid + 1] < want) {
            sh_prefix |= ((unsigned)tid << shift);
            sh_want = want - scan[tid + 1];
        }
        __syncthreads();
    }

    const unsigned T = sh_prefix;   // key of 64th-largest
    if (!ovf) {
        for (int i = tid; i < ccnt; i += 256) {
            const unsigned k = f2key(cval[i]);
            if (k > T) {
                const unsigned s = atomicAdd(&sh_cnt, 1u);
                sel[s] = cand[i];
                sval[s] = cval[i];
            } else if (k == T) {
                const unsigned s = atomicAdd(&sh_tiecnt, 1u);
                if (s < 256u) { ties[s] = cand[i]; tval[s] = cval[i]; }
            }
        }
    } else {
#pragma unroll
        for (int j = 0; j < 16; ++j) {
            const float fv[4] = { rv[j].x, rv[j].y, rv[j].z, rv[j].w };
#pragma unroll
            for (int q = 0; q < 4; ++q) {
                const unsigned k = f2key(fv[q]);
                if (k > T) {
                    const unsigned s = atomicAdd(&sh_cnt, 1u);
                    sel[s] = tid * 4 + j * 1024 + q;
                    sval[s] = fv[q];
                } else if (k == T) {
                    const unsigned s = atomicAdd(&sh_tiecnt, 1u);
                    if (s < 256u) { ties[s] = tid * 4 + j * 1024 + q; tval[s] = fv[q]; }
                }
            }
        }
    }
    __syncthreads();
    if (tid == 0) {
        const unsigned tc = sh_tiecnt;
        const int n = (int)(tc < 256u ? tc : 256u);
        for (int a = 1; a < n; ++a) {           // sort ties by index (with value)
            const int v = ties[a]; const float fv = tval[a]; int c = a;
            while (c > 0 && ties[c - 1] > v) {
                ties[c] = ties[c - 1]; tval[c] = tval[c - 1]; --c;
            }
            ties[c] = v; tval[c] = fv;
        }
        const int base = (int)sh_cnt;
        const int want = (int)sh_want;
        for (int j = 0; j < want && j < n; ++j) {
            sel[base + j] = ties[j]; sval[base + j] = tval[j];
        }
    }
    __syncthreads();
    if (tid < NK) {
        const int myi = sel[tid];
        int rank = 0;                            // canonical (ascending-idx) order
#pragma unroll 1
        for (int j = 0; j < NK; ++j) rank += (sel[j] < myi) ? 1 : 0;
        const float v = fmaxf(sval[tid], 0.f);   // relu
        tk_idx[b * NK + rank] = myi;
        tk_val[b * NK + rank] = v;
        zrow[myi] = v;
    }
}

// ---------------- inverse permutation ----------------
__global__ __launch_bounds__(256) void invperm_kernel(
    const int* __restrict__ perm, int* __restrict__ ipos)
{
    const int i = blockIdx.x * 256 + threadIdx.x;
    if (i < NT * NSAE) {
        const int t = i >> 14;
        ipos[t * NSAE + perm[i]] = i & (NSAE - 1);
    }
}

// ---------------- sparse decode + SSE partials (t-major grid) ----------------
__global__ __launch_bounds__(256) void decode_kernel(
    const float* __restrict__ x,
    const int* __restrict__ tk_idx, const float* __restrict__ tk_val,
    const int* __restrict__ ipos,
    const float* __restrict__ Wd0, const float* __restrict__ bd0,
    const float* __restrict__ Wd1, const float* __restrict__ bd1,
    float* __restrict__ xhat, float* __restrict__ part0, float* __restrict__ part1)
{
    const int gbid = blockIdx.x;
    const int t = gbid >> 10;
    const int b = gbid & (NB - 1);
    const int bt = b * NT + t;
    const int tid = threadIdx.x;

    __shared__ int s_p[NK];
    __shared__ float s_v[NK];
    if (tid < NK) {
        const int s = tk_idx[b * NK + tid];
        s_v[tid] = tk_val[b * NK + tid];
        s_p[tid] = ipos[t * NSAE + s];
    }
    __syncthreads();

    float acc0[3], acc1[3];
#pragma unroll
    for (int r = 0; r < 3; ++r) {
        const int d = tid + 256 * r;
        acc0[r] = bd0[t * NDIN + d];
        acc1[r] = bd1[t * NDIN + d];
    }
    for (int j = 0; j < NK; ++j) {
        const int p = s_p[j];
        const float v = s_v[j];
        const float* w1 = Wd1 + ((size_t)p * NT + t) * NDIN;
#pragma unroll
        for (int r = 0; r < 3; ++r) acc1[r] = fmaf(v, w1[tid + 256 * r], acc1[r]);
        if (p < PFX0) {
            const float* w0 = Wd0 + ((size_t)p * NT + t) * NDIN;
#pragma unroll
            for (int r = 0; r < 3; ++r) acc0[r] = fmaf(v, w0[tid + 256 * r], acc0[r]);
        }
    }

    float e0 = 0.f, e1 = 0.f;
#pragma unroll
    for (int r = 0; r < 3; ++r) {
        const int d = tid + 256 * r;
        const float xv = x[(size_t)bt * NDIN + d];
        const float d0 = acc0[r] - xv;
        const float d1 = acc1[r] - xv;
        e0 = fmaf(d0, d0, e0);
        e1 = fmaf(d1, d1, e1);
        xhat[(size_t)bt * NDIN + d] = acc1[r];
    }

    __shared__ float r0[256];
    __shared__ float r1[256];
    r0[tid] = e0; r1[tid] = e1;
    __syncthreads();
    for (int w2 = 128; w2 > 0; w2 >>= 1) {
        if (tid < w2) { r0[tid] += r0[tid + w2]; r1[tid] += r1[tid + w2]; }
        __syncthreads();
    }
    if (tid == 0) { part0[bt] = r0[0]; part1[bt] = r1[0]; }
}

// ---------------- final deterministic loss reduce ----------------
__global__ __launch_bounds__(256) void reduce_kernel(
    const float* __restrict__ part0, const float* __restrict__ part1,
    float* __restrict__ out_total)
{
    __shared__ double red[256];
    const int tid = threadIdx.x;
    double s = 0.0;
    for (int i = tid; i < NB * NT; i += 256)
        s += (double)part0[i] + (double)part1[i];
    red[tid] = s;
    __syncthreads();
    for (int w = 128; w > 0; w >>= 1) {
        if (tid < w) red[tid] += red[tid + w];
        __syncthreads();
    }
    if (tid == 0) out_total[0] = (float)(red[0] / ((double)NB * (double)(NT * 2)));
}

extern "C" void kernel_launch(void* const* d_in, const int* in_sizes, int n_in,
                              void* d_out, int out_size, void* d_ws, size_t ws_size,
                              hipStream_t stream)
{
    const float* x     = (const float*)d_in[0];
    const float* W_enc = (const float*)d_in[1];
    const float* b_enc = (const float*)d_in[2];
    const float* Wd0   = (const float*)d_in[3];
    const float* bd0   = (const float*)d_in[4];
    const float* Wd1   = (const float*)d_in[5];
    const float* bd1   = (const float*)d_in[6];
    const int*   perm  = (const int*)d_in[7];

    float* out       = (float*)d_out;
    float* out_total = out;
    float* out_xhat  = out + 1;
    float* out_z     = out + 1 + (size_t)NB * NT * NDIN;

    char* ws = (char*)d_ws;
    size_t off = 0;
    float* pre = (float*)(ws + off); off += (size_t)NB * NSAE * sizeof(float);

    const size_t szA2 = (size_t)NB * VKD * sizeof(_Float16);     // 12.6 MB
    _Float16* A2 = (_Float16*)(ws + off);
    const size_t off_splits_end = off + szA2;

    const bool fast = (ws_size >= off_splits_end +
        ((size_t)NB * NK * 8 + (size_t)NT * NSAE * 4 + (size_t)NB * NT * 8));
    size_t tail = fast ? off_splits_end : off;
    int*   tk_idx = (int*)(ws + tail);   tail += (size_t)NB * NK * sizeof(int);
    float* tk_val = (float*)(ws + tail); tail += (size_t)NB * NK * sizeof(float);
    int*   ipos   = (int*)(ws + tail);   tail += (size_t)NT * NSAE * sizeof(int);
    float* part0  = (float*)(ws + tail); tail += (size_t)NB * NT * sizeof(float);
    float* part1  = (float*)(ws + tail);

    if (fast) {
        conv_a_kernel<<<(NB * KDIM) / (256 * 4), 256, 0, stream>>>(x, A2);
        gemm_f16split_kernel<<<256, 512, 0, stream>>>(A2, W_enc, b_enc, pre);
    } else {
        gemm_pre_kernel<<<dim3(NSAE / 128, NB / 128), 256, 0, stream>>>(x, W_enc, b_enc, pre);
    }
    invperm_kernel<<<(NT * NSAE) / 256, 256, 0, stream>>>(perm, ipos);
    topk_kernel<<<NB, 256, 0, stream>>>(pre, tk_idx, tk_val, out_z);
    decode_kernel<<<NB * NT, 256, 0, stream>>>(x, tk_idx, tk_val, ipos,
                                               Wd0, bd0, Wd1, bd1,
                                               out_xhat, part0, part1);
    reduce_kernel<<<1, 256, 0, stream>>>(part0, part1, out_total);
}